// Round 5
// baseline (1488.529 us; speedup 1.0000x reference)
//
#include <hip/hip_runtime.h>
#include <math.h>

#define TPB 256
#define BSH 7          // bucket = dst >> 7  (128 nodes/bucket)
#define NBMAX 1024     // max buckets supported (n <= 131072)

__device__ __forceinline__ float leaky02(float x) { return x > 0.f ? x : 0.2f * x; }
__device__ __forceinline__ float eluf(float x) { return x > 0.f ? x : (expf(x) - 1.f); }

// ====================== CSR build: bucketed counting sort by dst ======================

__global__ void zero_kernel(int* __restrict__ p, int n) {
  int i = blockIdx.x * blockDim.x + threadIdx.x;
  if (i < n) p[i] = 0;
}

// LDS-aggregated bucket histogram over edges (+ self loops), grid-stride.
__global__ void bucket_hist_kernel(const int* __restrict__ dst, int E, int n,
                                   int* __restrict__ bcount) {
  __shared__ int lh[NBMAX];
  for (int j = threadIdx.x; j < NBMAX; j += blockDim.x) lh[j] = 0;
  __syncthreads();
  int stride = gridDim.x * blockDim.x;
  for (int idx = blockIdx.x * blockDim.x + threadIdx.x; idx < E + n; idx += stride) {
    int dd = (idx < E) ? dst[idx] : (idx - E);
    atomicAdd(&lh[dd >> BSH], 1);
  }
  __syncthreads();
  for (int j = threadIdx.x; j < NBMAX; j += blockDim.x) {
    int v = lh[j];
    if (v) atomicAdd(&bcount[j], v);
  }
}

// exclusive scan of bcount in place (nb <= 1024), single block of 1024
__global__ void scan1024_kernel(int* __restrict__ a, int nb) {
  __shared__ int sm[NBMAX];
  int t = threadIdx.x;
  int v = (t < nb) ? a[t] : 0;
  sm[t] = v;
  __syncthreads();
  for (int off = 1; off < NBMAX; off <<= 1) {
    int x = (t >= off) ? sm[t - off] : 0;
    __syncthreads();
    sm[t] += x;
    __syncthreads();
  }
  if (t < nb) a[t] = sm[t] - v;  // exclusive
}

// scatter (src,dst) pairs into bucket-sorted tmp; bcount acts as cursor.
__global__ void bucket_scatter_kernel(const int* __restrict__ src, const int* __restrict__ dst,
                                      int E, int n, int* __restrict__ bcursor,
                                      int2* __restrict__ tmp) {
  int idx = blockIdx.x * blockDim.x + threadIdx.x;
  if (idx >= E + n) return;
  int ss, dd;
  if (idx < E) { ss = src[idx]; dd = dst[idx]; }
  else         { ss = dd = idx - E; }
  int pos = atomicAdd(&bcursor[dd >> BSH], 1);
  tmp[pos] = make_int2(ss, dd);
}

// degree histogram over bucket-sorted tmp (atomics land in L2-local 128-node windows)
__global__ void hist2_kernel(const int2* __restrict__ tmp, int Etot, int* __restrict__ deg) {
  int idx = blockIdx.x * blockDim.x + threadIdx.x;
  if (idx >= Etot) return;
  atomicAdd(&deg[tmp[idx].y], 1);
}

// per-block reduce of deg -> bsum[block]
__global__ void scanA_kernel(const int* __restrict__ deg, int n, int* __restrict__ bsum) {
  __shared__ int sm[TPB];
  int i = blockIdx.x * TPB + threadIdx.x;
  sm[threadIdx.x] = (i < n) ? deg[i] : 0;
  __syncthreads();
  for (int off = TPB / 2; off >= 1; off >>= 1) {
    if (threadIdx.x < off) sm[threadIdx.x] += sm[threadIdx.x + off];
    __syncthreads();
  }
  if (threadIdx.x == 0) bsum[blockIdx.x] = sm[0];
}

// single block of 512: exclusive scan of bsum in place (nb <= 512)
__global__ void scanB_kernel(int* __restrict__ bsum, int nb) {
  __shared__ int sm[512];
  int t = threadIdx.x;
  int v = (t < nb) ? bsum[t] : 0;
  sm[t] = v;
  __syncthreads();
  for (int off = 1; off < 512; off <<= 1) {
    int a = (t >= off) ? sm[t - off] : 0;
    __syncthreads();
    sm[t] += a;
    __syncthreads();
  }
  if (t < nb) bsum[t] = sm[t] - v;  // exclusive
}

// per-block exclusive scan + block offset -> rowptr, cursor
__global__ void scanC_kernel(const int* __restrict__ deg, const int* __restrict__ boff, int n,
                             int* __restrict__ rowptr, int* __restrict__ cursor) {
  __shared__ int sm[TPB];
  int t = threadIdx.x;
  int i = blockIdx.x * TPB + t;
  int v = (i < n) ? deg[i] : 0;
  sm[t] = v;
  __syncthreads();
  for (int off = 1; off < TPB; off <<= 1) {
    int a = (t >= off) ? sm[t - off] : 0;
    __syncthreads();
    sm[t] += a;
    __syncthreads();
  }
  if (i < n) {
    int ex = boff[blockIdx.x] + sm[t] - v;
    rowptr[i] = ex;
    cursor[i] = ex;
  }
}

// final scatter from bucket-sorted tmp: cursor atomics + csr writes stay in L2-local windows
__global__ void final_scatter_kernel(const int2* __restrict__ tmp, int Etot,
                                     int* __restrict__ cursor, int* __restrict__ csr_src) {
  int idx = blockIdx.x * blockDim.x + threadIdx.x;
  if (idx >= Etot) return;
  int2 e = tmp[idx];
  int pos = atomicAdd(&cursor[e.y], 1);
  csr_src[pos] = e.x;
}

// ====================== node transform (h = x@W, attn logits) ======================

template<int IN, int OUT, int H>
__global__ void transform_kernel(const float* __restrict__ x, const float* __restrict__ W,
                                 const float* __restrict__ a_src, const float* __restrict__ a_dst,
                                 float* __restrict__ h, float* __restrict__ asrc,
                                 float* __restrict__ adst, int n) {
  __shared__ float sW[IN * OUT];
  __shared__ float sa[2 * OUT];
  for (int i = threadIdx.x; i < IN * OUT; i += blockDim.x) sW[i] = W[i];
  if (threadIdx.x < OUT) {
    sa[threadIdx.x] = a_src[threadIdx.x];
    sa[OUT + threadIdx.x] = a_dst[threadIdx.x];
  }
  __syncthreads();
  int i = blockIdx.x * blockDim.x + threadIdx.x;
  if (i >= n) return;
  float xv[IN];
#pragma unroll
  for (int k = 0; k < IN; k++) xv[k] = x[(size_t)i * IN + k];
  float hv[OUT];
#pragma unroll
  for (int j = 0; j < OUT; j++) {
    float acc = 0.f;
#pragma unroll
    for (int k = 0; k < IN; k++) acc += xv[k] * sW[k * OUT + j];
    hv[j] = acc;
    h[(size_t)i * OUT + j] = acc;
  }
#pragma unroll
  for (int hh = 0; hh < H; hh++) {
    float as = 0.f, ad = 0.f;
#pragma unroll
    for (int c = 0; c < 16; c++) {
      as += hv[hh * 16 + c] * sa[hh * 16 + c];
      ad += hv[hh * 16 + c] * sa[OUT + hh * 16 + c];
    }
    asrc[i * H + hh] = as;
    adst[i * H + hh] = ad;
  }
}

// ====================== per-node GAT aggregation (1 wave / dst node) ======================
// Pass 1: fused online softmax (running m,s per lane, shfl-xor merge).
// Pass 2: stage (sidx, alpha) in LDS, strided gather-accumulate (verified in R4).

__global__ __launch_bounds__(256) void node_gat12(
    const int* __restrict__ rowptr, const int* __restrict__ deg,
    const int* __restrict__ csr_src,
    const float* __restrict__ asrc,  // [n*2]
    const float* __restrict__ adst,  // [n*2]
    const float* __restrict__ hfeat, // [n*32]
    const float* __restrict__ bias,  // [32]
    float* __restrict__ outb,        // [n*32]
    int n) {
  __shared__ int   s_sidx[4][64];
  __shared__ float s_a0[4][64];
  __shared__ float s_a1[4][64];
  int wid = threadIdx.x >> 6;
  int lane = threadIdx.x & 63;
  int i = (blockIdx.x * blockDim.x + threadIdx.x) >> 6;
  if (i >= n) return;
  int start = rowptr[i];
  int d = deg[i];
  float ad0 = adst[i * 2 + 0];
  float ad1 = adst[i * 2 + 1];

  // ---- pass 1: online softmax (max + expsum in one sweep) ----
  float m0 = -3.4e38f, s0 = 0.f, m1 = -3.4e38f, s1 = 0.f;
  for (int k = lane; k < d; k += 64) {
    int sidx = csr_src[start + k];
    float2 av = ((const float2*)asrc)[sidx];
    float e0 = leaky02(av.x + ad0);
    float e1 = leaky02(av.y + ad1);
    float nm0 = fmaxf(m0, e0);
    s0 = s0 * expf(m0 - nm0) + expf(e0 - nm0);
    m0 = nm0;
    float nm1 = fmaxf(m1, e1);
    s1 = s1 * expf(m1 - nm1) + expf(e1 - nm1);
    m1 = nm1;
  }
#pragma unroll
  for (int off = 32; off >= 1; off >>= 1) {
    float mo0 = __shfl_xor(m0, off), so0 = __shfl_xor(s0, off);
    float nm0 = fmaxf(m0, mo0);
    s0 = s0 * expf(m0 - nm0) + so0 * expf(mo0 - nm0);
    m0 = nm0;
    float mo1 = __shfl_xor(m1, off), so1 = __shfl_xor(s1, off);
    float nm1 = fmaxf(m1, mo1);
    s1 = s1 * expf(m1 - nm1) + so1 * expf(mo1 - nm1);
    m1 = nm1;
  }
  float inv0 = 1.f / (s0 + 1e-16f);
  float inv1 = 1.f / (s1 + 1e-16f);

  // ---- pass 2: per-edge alpha staged in LDS; strided gather-accumulate ----
  int head = (lane >> 4) & 1;   // head of my channel
  int c = lane & 31;            // my channel (0..31)
  int half = lane >> 5;         // which parity of edges I accumulate
  float acc = 0.f;
  for (int base = 0; base < d; base += 64) {
    int k = base + lane;
    int sidx = 0;
    float a0 = 0.f, a1 = 0.f;
    if (k < d) {
      sidx = csr_src[start + k];
      float2 av = ((const float2*)asrc)[sidx];
      a0 = expf(leaky02(av.x + ad0) - m0) * inv0;
      a1 = expf(leaky02(av.y + ad1) - m1) * inv1;
    }
    s_sidx[wid][lane] = sidx;
    s_a0[wid][lane] = a0;
    s_a1[wid][lane] = a1;
    // same-wave LDS write->read: DS pipe processes a wave's ops in order.
    int cnt = min(64, d - base);
    for (int jj = half; jj < cnt; jj += 2) {
      int sb = s_sidx[wid][jj];
      float wb = head ? s_a1[wid][jj] : s_a0[wid][jj];
      acc += wb * hfeat[(size_t)sb * 32 + c];
    }
  }
  acc += __shfl_xor(acc, 32);
  if (lane < 32) {
    outb[(size_t)i * 32 + c] = eluf(acc + bias[c]);
  }
}

// H=1, C=16 (layer 3) + fused output head.
__global__ __launch_bounds__(256) void node_gat3(
    const int* __restrict__ rowptr, const int* __restrict__ deg,
    const int* __restrict__ csr_src,
    const float* __restrict__ asrc,  // [n]
    const float* __restrict__ adst,  // [n]
    const float* __restrict__ hfeat, // [n*16]
    const float* __restrict__ b3,    // [16]
    const float* __restrict__ Wout,  // [16]
    const float* __restrict__ bout,  // [1]
    float* __restrict__ out,         // [n] sigmoid ++ [n*16] embeddings
    int n) {
  __shared__ int   s_sidx[4][64];
  __shared__ float s_a0[4][64];
  int wid = threadIdx.x >> 6;
  int lane = threadIdx.x & 63;
  int i = (blockIdx.x * blockDim.x + threadIdx.x) >> 6;
  if (i >= n) return;
  int start = rowptr[i];
  int d = deg[i];
  float ad0 = adst[i];

  // ---- pass 1: online softmax ----
  float m0 = -3.4e38f, s0 = 0.f;
  for (int k = lane; k < d; k += 64) {
    int sidx = csr_src[start + k];
    float e0 = leaky02(asrc[sidx] + ad0);
    float nm0 = fmaxf(m0, e0);
    s0 = s0 * expf(m0 - nm0) + expf(e0 - nm0);
    m0 = nm0;
  }
#pragma unroll
  for (int off = 32; off >= 1; off >>= 1) {
    float mo = __shfl_xor(m0, off), so = __shfl_xor(s0, off);
    float nm = fmaxf(m0, mo);
    s0 = s0 * expf(m0 - nm) + so * expf(mo - nm);
    m0 = nm;
  }
  float inv = 1.f / (s0 + 1e-16f);

  // ---- pass 2: staged alpha + strided gather ----
  int c = lane & 15;
  int quarter = lane >> 4;  // 0..3
  float acc = 0.f;
  for (int base = 0; base < d; base += 64) {
    int k = base + lane;
    int sidx = 0;
    float a0 = 0.f;
    if (k < d) {
      sidx = csr_src[start + k];
      a0 = expf(leaky02(asrc[sidx] + ad0) - m0) * inv;
    }
    s_sidx[wid][lane] = sidx;
    s_a0[wid][lane] = a0;
    int cnt = min(64, d - base);
    for (int jj = quarter; jj < cnt; jj += 4) {
      int sb = s_sidx[wid][jj];
      acc += s_a0[wid][jj] * hfeat[(size_t)sb * 16 + c];
    }
  }
  acc += __shfl_xor(acc, 32);
  acc += __shfl_xor(acc, 16);

  float v = 0.f, z = 0.f;
  if (lane < 16) {
    v = eluf(acc + b3[c]);
    out[(size_t)n + (size_t)i * 16 + c] = v;
    z = v * Wout[c];
  }
#pragma unroll
  for (int off = 8; off >= 1; off >>= 1) z += __shfl_xor(z, off);
  if (lane == 0) out[i] = 1.f / (1.f + expf(-(z + bout[0])));
}

// ====================== launch ======================

extern "C" void kernel_launch(void* const* d_in, const int* in_sizes, int n_in,
                              void* d_out, int out_size, void* d_ws, size_t ws_size,
                              hipStream_t stream) {
  const float* x    = (const float*)d_in[0];
  const int*   ei   = (const int*)d_in[1];
  const float* W1   = (const float*)d_in[2];
  const float* as1  = (const float*)d_in[3];
  const float* ad1  = (const float*)d_in[4];
  const float* b1   = (const float*)d_in[5];
  const float* W2   = (const float*)d_in[6];
  const float* as2  = (const float*)d_in[7];
  const float* ad2  = (const float*)d_in[8];
  const float* b2   = (const float*)d_in[9];
  const float* W3   = (const float*)d_in[10];
  const float* as3  = (const float*)d_in[11];
  const float* ad3  = (const float*)d_in[12];
  const float* b3   = (const float*)d_in[13];
  const float* Wout = (const float*)d_in[14];
  const float* bout = (const float*)d_in[15];
  float* out = (float*)d_out;

  const int n = in_sizes[0] / 3;
  const int E = in_sizes[1] / 2;
  const int Etot = E + n;
  const int* src = ei;
  const int* dst = ei + E;
  const int NB = ((n - 1) >> BSH) + 1;  // buckets (n=100000 -> 782, <= 1024)

  // workspace layout
  // floats region (27.2 MB for n=100k) — transient CSR tmp (int2 x Etot = 26.4 MB) aliases it,
  // dead before the first transform_kernel writes bufH/asrc/adst.
  float* ws = (float*)d_ws;
  float* bufH = ws;                               // n*32
  float* bufX = bufH + (size_t)n * 32;            // n*32
  float* asrc = bufX + (size_t)n * 32;            // n*2
  float* adst = asrc + (size_t)n * 2;             // n*2
  int* rowptr  = (int*)(adst + (size_t)n * 2);    // n
  int* deg     = rowptr + n;                      // n
  int* bcount  = deg + n;                         // NBMAX (adjacent to deg: zeroed together)
  int* cursor  = bcount + NBMAX;                  // n
  int* bsum    = cursor + n;                      // 512
  int* csr_src = bsum + 512;                      // E+n
  int2* tmp    = (int2*)ws;                       // Etot (aliases bufH..adst)

  const int nbN = (n + TPB - 1) / TPB;
  const int nbE = (Etot + TPB - 1) / TPB;
  const int nbW = (n + 3) / 4;  // 1 wave per node, 4 waves/block

  // ---- CSR build: bucketed counting sort (once, reused by all 3 layers) ----
  zero_kernel<<<(n + NBMAX + TPB - 1) / TPB, TPB, 0, stream>>>(deg, n + NBMAX);  // deg + bcount
  bucket_hist_kernel<<<512, TPB, 0, stream>>>(dst, E, n, bcount);
  scan1024_kernel<<<1, NBMAX, 0, stream>>>(bcount, NB);
  bucket_scatter_kernel<<<nbE, TPB, 0, stream>>>(src, dst, E, n, bcount, tmp);
  hist2_kernel<<<nbE, TPB, 0, stream>>>(tmp, Etot, deg);
  scanA_kernel<<<nbN, TPB, 0, stream>>>(deg, n, bsum);
  scanB_kernel<<<1, 512, 0, stream>>>(bsum, nbN);
  scanC_kernel<<<nbN, TPB, 0, stream>>>(deg, bsum, n, rowptr, cursor);
  final_scatter_kernel<<<nbE, TPB, 0, stream>>>(tmp, Etot, cursor, csr_src);

  // ---- layer 1: in=3, out=32, H=2 ----
  transform_kernel<3, 32, 2><<<nbN, TPB, 0, stream>>>(x, W1, as1, ad1, bufH, asrc, adst, n);
  node_gat12<<<nbW, TPB, 0, stream>>>(rowptr, deg, csr_src, asrc, adst, bufH, b1, bufX, n);

  // ---- layer 2: in=32, out=32, H=2 ----
  transform_kernel<32, 32, 2><<<nbN, TPB, 0, stream>>>(bufX, W2, as2, ad2, bufH, asrc, adst, n);
  node_gat12<<<nbW, TPB, 0, stream>>>(rowptr, deg, csr_src, asrc, adst, bufH, b2, bufX, n);

  // ---- layer 3: in=32, out=16, H=1 ----
  transform_kernel<32, 16, 1><<<nbN, TPB, 0, stream>>>(bufX, W3, as3, ad3, bufH, asrc, adst, n);
  node_gat3<<<nbW, TPB, 0, stream>>>(rowptr, deg, csr_src, asrc, adst, bufH, b3, Wout, bout, out, n);
}

// Round 6
// 1001.569 us; speedup vs baseline: 1.4862x; 1.4862x over previous
//
#include <hip/hip_runtime.h>
#include <math.h>

#define TPB 256
#define P 8            // dst partitions
#define PSH 14         // partition = dst >> 14 (16384 nodes/partition, n <= 131072)
#define CAP 512        // LDS staging buffer entries per partition

__device__ __forceinline__ float leaky02(float x) { return x > 0.f ? x : 0.2f * x; }
__device__ __forceinline__ float eluf(float x) { return x > 0.f ? x : (expf(x) - 1.f); }

// ====================== CSR build: partition-staged counting sort by dst ======================

__global__ void zero_kernel(int* __restrict__ p, int n) {
  int i = blockIdx.x * blockDim.x + threadIdx.x;
  if (i < n) p[i] = 0;
}

// per-partition edge counts (LDS-aggregated, 8 counters)
__global__ void phist_kernel(const int* __restrict__ dst, int E, int n, int* __restrict__ pcount) {
  __shared__ int lh[P];
  if (threadIdx.x < P) lh[threadIdx.x] = 0;
  __syncthreads();
  int stride = gridDim.x * blockDim.x;
  for (int idx = blockIdx.x * blockDim.x + threadIdx.x; idx < E + n; idx += stride) {
    int dd = (idx < E) ? dst[idx] : (idx - E);
    atomicAdd(&lh[min(dd >> PSH, P - 1)], 1);
  }
  __syncthreads();
  if (threadIdx.x < P) {
    int v = lh[threadIdx.x];
    if (v) atomicAdd(&pcount[threadIdx.x], v);
  }
}

// exclusive scan of 8 partition counts -> pcursor (= partition base offsets)
__global__ void pscan_kernel(const int* __restrict__ pcount, int* __restrict__ pcursor) {
  if (threadIdx.x == 0) {
    int acc = 0;
    for (int q = 0; q < P; q++) { int v = pcount[q]; pcursor[q] = acc; acc += v; }
  }
}

// LDS-buffered partition scatter: bursts of >=256 contiguous int2 per global atomic.
__global__ __launch_bounds__(256) void stage_kernel(const int* __restrict__ src,
                                                    const int* __restrict__ dst,
                                                    int E, int n,
                                                    int* __restrict__ pcursor,
                                                    int2* __restrict__ pstage) {
  __shared__ int2 buf[P][CAP];
  __shared__ int cnt[P];
  __shared__ int gbase;
  if (threadIdx.x < P) cnt[threadIdx.x] = 0;
  __syncthreads();
  int Etot = E + n;
  int tiles = (Etot + TPB - 1) / TPB;
  for (int t = blockIdx.x; t < tiles; t += gridDim.x) {
    int idx = t * TPB + threadIdx.x;
    if (idx < Etot) {
      int ss, dd;
      if (idx < E) { ss = src[idx]; dd = dst[idx]; }
      else         { ss = dd = idx - E; }
      int p = min(dd >> PSH, P - 1);
      int pos = atomicAdd(&cnt[p], 1);   // LDS atomic; pos < CAP guaranteed (flush below)
      buf[p][pos] = make_int2(ss, dd);
    }
    __syncthreads();
    // flush any buffer >= 256 so next 256-edge tile cannot overflow CAP=512
    for (int q = 0; q < P; q++) {
      int c = cnt[q];
      if (c >= 256) {
        if (threadIdx.x == 0) gbase = atomicAdd(&pcursor[q], c);
        __syncthreads();
        for (int j = threadIdx.x; j < c; j += TPB) pstage[gbase + j] = buf[q][j];
        __syncthreads();
        if (threadIdx.x == 0) cnt[q] = 0;
        __syncthreads();
      }
    }
  }
  // final flush of residuals
  for (int q = 0; q < P; q++) {
    int c = cnt[q];
    if (c > 0) {
      if (threadIdx.x == 0) gbase = atomicAdd(&pcursor[q], c);
      __syncthreads();
      for (int j = threadIdx.x; j < c; j += TPB) pstage[gbase + j] = buf[q][j];
      __syncthreads();
      if (threadIdx.x == 0) cnt[q] = 0;
      __syncthreads();
    }
  }
}

// degree histogram over partition-staged pairs (sequential reads; atomics in narrow windows)
__global__ void deg_hist_kernel(const int2* __restrict__ pstage, int Etot, int* __restrict__ deg) {
  int idx = blockIdx.x * blockDim.x + threadIdx.x;
  if (idx >= Etot) return;
  atomicAdd(&deg[pstage[idx].y], 1);
}

// per-block reduce of deg -> bsum[block]
__global__ void scanA_kernel(const int* __restrict__ deg, int n, int* __restrict__ bsum) {
  __shared__ int sm[TPB];
  int i = blockIdx.x * TPB + threadIdx.x;
  sm[threadIdx.x] = (i < n) ? deg[i] : 0;
  __syncthreads();
  for (int off = TPB / 2; off >= 1; off >>= 1) {
    if (threadIdx.x < off) sm[threadIdx.x] += sm[threadIdx.x + off];
    __syncthreads();
  }
  if (threadIdx.x == 0) bsum[blockIdx.x] = sm[0];
}

// single block of 512: exclusive scan of bsum in place (nb <= 512)
__global__ void scanB_kernel(int* __restrict__ bsum, int nb) {
  __shared__ int sm[512];
  int t = threadIdx.x;
  int v = (t < nb) ? bsum[t] : 0;
  sm[t] = v;
  __syncthreads();
  for (int off = 1; off < 512; off <<= 1) {
    int a = (t >= off) ? sm[t - off] : 0;
    __syncthreads();
    sm[t] += a;
    __syncthreads();
  }
  if (t < nb) bsum[t] = sm[t] - v;  // exclusive
}

// per-block exclusive scan + block offset -> rowptr, cursor
__global__ void scanC_kernel(const int* __restrict__ deg, const int* __restrict__ boff, int n,
                             int* __restrict__ rowptr, int* __restrict__ cursor) {
  __shared__ int sm[TPB];
  int t = threadIdx.x;
  int i = blockIdx.x * TPB + t;
  int v = (i < n) ? deg[i] : 0;
  sm[t] = v;
  __syncthreads();
  for (int off = 1; off < TPB; off <<= 1) {
    int a = (t >= off) ? sm[t - off] : 0;
    __syncthreads();
    sm[t] += a;
    __syncthreads();
  }
  if (i < n) {
    int ex = boff[blockIdx.x] + sm[t] - v;
    rowptr[i] = ex;
    cursor[i] = ex;
  }
}

// final scatter: XCD-swizzled chunks keep each XCD's csr writes in one L2-resident window.
__global__ void final_scatter_kernel(const int2* __restrict__ pstage, int Etot, int G8,
                                     int* __restrict__ cursor, int* __restrict__ csr_src) {
  int b = blockIdx.x;
  int c = (b & 7) * G8 + (b >> 3);   // XCD k (~ b%8) -> contiguous chunk range
  int idx = c * TPB + threadIdx.x;
  if (idx >= Etot) return;
  int2 e = pstage[idx];
  int pos = atomicAdd(&cursor[e.y], 1);
  csr_src[pos] = e.x;
}

// ====================== node transform (h = x@W, attn logits) ======================

template<int IN, int OUT, int H>
__global__ void transform_kernel(const float* __restrict__ x, const float* __restrict__ W,
                                 const float* __restrict__ a_src, const float* __restrict__ a_dst,
                                 float* __restrict__ h, float* __restrict__ asrc,
                                 float* __restrict__ adst, int n) {
  __shared__ float sW[IN * OUT];
  __shared__ float sa[2 * OUT];
  for (int i = threadIdx.x; i < IN * OUT; i += blockDim.x) sW[i] = W[i];
  if (threadIdx.x < OUT) {
    sa[threadIdx.x] = a_src[threadIdx.x];
    sa[OUT + threadIdx.x] = a_dst[threadIdx.x];
  }
  __syncthreads();
  int i = blockIdx.x * blockDim.x + threadIdx.x;
  if (i >= n) return;
  float xv[IN];
#pragma unroll
  for (int k = 0; k < IN; k++) xv[k] = x[(size_t)i * IN + k];
  float hv[OUT];
#pragma unroll
  for (int j = 0; j < OUT; j++) {
    float acc = 0.f;
#pragma unroll
    for (int k = 0; k < IN; k++) acc += xv[k] * sW[k * OUT + j];
    hv[j] = acc;
    h[(size_t)i * OUT + j] = acc;
  }
#pragma unroll
  for (int hh = 0; hh < H; hh++) {
    float as = 0.f, ad = 0.f;
#pragma unroll
    for (int c = 0; c < 16; c++) {
      as += hv[hh * 16 + c] * sa[hh * 16 + c];
      ad += hv[hh * 16 + c] * sa[OUT + hh * 16 + c];
    }
    asrc[i * H + hh] = as;
    adst[i * H + hh] = ad;
  }
}

// ====================== per-node GAT aggregation (1 wave / dst node) ======================
// Pass 1: fused online softmax (verified R5). Pass 2: LDS-staged strided gather (verified R4).

__global__ __launch_bounds__(256) void node_gat12(
    const int* __restrict__ rowptr, const int* __restrict__ deg,
    const int* __restrict__ csr_src,
    const float* __restrict__ asrc,  // [n*2]
    const float* __restrict__ adst,  // [n*2]
    const float* __restrict__ hfeat, // [n*32]
    const float* __restrict__ bias,  // [32]
    float* __restrict__ outb,        // [n*32]
    int n) {
  __shared__ int   s_sidx[4][64];
  __shared__ float s_a0[4][64];
  __shared__ float s_a1[4][64];
  int wid = threadIdx.x >> 6;
  int lane = threadIdx.x & 63;
  int i = (blockIdx.x * blockDim.x + threadIdx.x) >> 6;
  if (i >= n) return;
  int start = rowptr[i];
  int d = deg[i];
  float ad0 = adst[i * 2 + 0];
  float ad1 = adst[i * 2 + 1];

  // ---- pass 1: online softmax (max + expsum in one sweep) ----
  float m0 = -3.4e38f, s0 = 0.f, m1 = -3.4e38f, s1 = 0.f;
  for (int k = lane; k < d; k += 64) {
    int sidx = csr_src[start + k];
    float2 av = ((const float2*)asrc)[sidx];
    float e0 = leaky02(av.x + ad0);
    float e1 = leaky02(av.y + ad1);
    float nm0 = fmaxf(m0, e0);
    s0 = s0 * expf(m0 - nm0) + expf(e0 - nm0);
    m0 = nm0;
    float nm1 = fmaxf(m1, e1);
    s1 = s1 * expf(m1 - nm1) + expf(e1 - nm1);
    m1 = nm1;
  }
#pragma unroll
  for (int off = 32; off >= 1; off >>= 1) {
    float mo0 = __shfl_xor(m0, off), so0 = __shfl_xor(s0, off);
    float nm0 = fmaxf(m0, mo0);
    s0 = s0 * expf(m0 - nm0) + so0 * expf(mo0 - nm0);
    m0 = nm0;
    float mo1 = __shfl_xor(m1, off), so1 = __shfl_xor(s1, off);
    float nm1 = fmaxf(m1, mo1);
    s1 = s1 * expf(m1 - nm1) + so1 * expf(mo1 - nm1);
    m1 = nm1;
  }
  float inv0 = 1.f / (s0 + 1e-16f);
  float inv1 = 1.f / (s1 + 1e-16f);

  // ---- pass 2: per-edge alpha staged in LDS; strided gather-accumulate ----
  int head = (lane >> 4) & 1;   // head of my channel
  int c = lane & 31;            // my channel (0..31)
  int half = lane >> 5;         // which parity of edges I accumulate
  float acc = 0.f;
  for (int base = 0; base < d; base += 64) {
    int k = base + lane;
    int sidx = 0;
    float a0 = 0.f, a1 = 0.f;
    if (k < d) {
      sidx = csr_src[start + k];
      float2 av = ((const float2*)asrc)[sidx];
      a0 = expf(leaky02(av.x + ad0) - m0) * inv0;
      a1 = expf(leaky02(av.y + ad1) - m1) * inv1;
    }
    s_sidx[wid][lane] = sidx;
    s_a0[wid][lane] = a0;
    s_a1[wid][lane] = a1;
    // same-wave LDS write->read: DS pipe processes a wave's ops in order.
    int cnt = min(64, d - base);
    for (int jj = half; jj < cnt; jj += 2) {
      int sb = s_sidx[wid][jj];
      float wb = head ? s_a1[wid][jj] : s_a0[wid][jj];
      acc += wb * hfeat[(size_t)sb * 32 + c];
    }
  }
  acc += __shfl_xor(acc, 32);
  if (lane < 32) {
    outb[(size_t)i * 32 + c] = eluf(acc + bias[c]);
  }
}

// H=1, C=16 (layer 3) + fused output head.
__global__ __launch_bounds__(256) void node_gat3(
    const int* __restrict__ rowptr, const int* __restrict__ deg,
    const int* __restrict__ csr_src,
    const float* __restrict__ asrc,  // [n]
    const float* __restrict__ adst,  // [n]
    const float* __restrict__ hfeat, // [n*16]
    const float* __restrict__ b3,    // [16]
    const float* __restrict__ Wout,  // [16]
    const float* __restrict__ bout,  // [1]
    float* __restrict__ out,         // [n] sigmoid ++ [n*16] embeddings
    int n) {
  __shared__ int   s_sidx[4][64];
  __shared__ float s_a0[4][64];
  int wid = threadIdx.x >> 6;
  int lane = threadIdx.x & 63;
  int i = (blockIdx.x * blockDim.x + threadIdx.x) >> 6;
  if (i >= n) return;
  int start = rowptr[i];
  int d = deg[i];
  float ad0 = adst[i];

  // ---- pass 1: online softmax ----
  float m0 = -3.4e38f, s0 = 0.f;
  for (int k = lane; k < d; k += 64) {
    int sidx = csr_src[start + k];
    float e0 = leaky02(asrc[sidx] + ad0);
    float nm0 = fmaxf(m0, e0);
    s0 = s0 * expf(m0 - nm0) + expf(e0 - nm0);
    m0 = nm0;
  }
#pragma unroll
  for (int off = 32; off >= 1; off >>= 1) {
    float mo = __shfl_xor(m0, off), so = __shfl_xor(s0, off);
    float nm = fmaxf(m0, mo);
    s0 = s0 * expf(m0 - nm) + so * expf(mo - nm);
    m0 = nm;
  }
  float inv = 1.f / (s0 + 1e-16f);

  // ---- pass 2: staged alpha + strided gather ----
  int c = lane & 15;
  int quarter = lane >> 4;  // 0..3
  float acc = 0.f;
  for (int base = 0; base < d; base += 64) {
    int k = base + lane;
    int sidx = 0;
    float a0 = 0.f;
    if (k < d) {
      sidx = csr_src[start + k];
      a0 = expf(leaky02(asrc[sidx] + ad0) - m0) * inv;
    }
    s_sidx[wid][lane] = sidx;
    s_a0[wid][lane] = a0;
    int cnt = min(64, d - base);
    for (int jj = quarter; jj < cnt; jj += 4) {
      int sb = s_sidx[wid][jj];
      acc += s_a0[wid][jj] * hfeat[(size_t)sb * 16 + c];
    }
  }
  acc += __shfl_xor(acc, 32);
  acc += __shfl_xor(acc, 16);

  float v = 0.f, z = 0.f;
  if (lane < 16) {
    v = eluf(acc + b3[c]);
    out[(size_t)n + (size_t)i * 16 + c] = v;
    z = v * Wout[c];
  }
#pragma unroll
  for (int off = 8; off >= 1; off >>= 1) z += __shfl_xor(z, off);
  if (lane == 0) out[i] = 1.f / (1.f + expf(-(z + bout[0])));
}

// ====================== launch ======================

extern "C" void kernel_launch(void* const* d_in, const int* in_sizes, int n_in,
                              void* d_out, int out_size, void* d_ws, size_t ws_size,
                              hipStream_t stream) {
  const float* x    = (const float*)d_in[0];
  const int*   ei   = (const int*)d_in[1];
  const float* W1   = (const float*)d_in[2];
  const float* as1  = (const float*)d_in[3];
  const float* ad1  = (const float*)d_in[4];
  const float* b1   = (const float*)d_in[5];
  const float* W2   = (const float*)d_in[6];
  const float* as2  = (const float*)d_in[7];
  const float* ad2  = (const float*)d_in[8];
  const float* b2   = (const float*)d_in[9];
  const float* W3   = (const float*)d_in[10];
  const float* as3  = (const float*)d_in[11];
  const float* ad3  = (const float*)d_in[12];
  const float* b3   = (const float*)d_in[13];
  const float* Wout = (const float*)d_in[14];
  const float* bout = (const float*)d_in[15];
  float* out = (float*)d_out;

  const int n = in_sizes[0] / 3;
  const int E = in_sizes[1] / 2;
  const int Etot = E + n;
  const int* src = ei;
  const int* dst = ei + E;

  // workspace layout
  // float region (27.2 MB) — transient pstage (int2 x Etot = 26.4 MB) aliases it; pstage is
  // dead before the first transform_kernel writes bufH/asrc/adst.
  float* ws = (float*)d_ws;
  float* bufH = ws;                               // n*32
  float* bufX = bufH + (size_t)n * 32;            // n*32
  float* asrc = bufX + (size_t)n * 32;            // n*2
  float* adst = asrc + (size_t)n * 2;             // n*2
  int* rowptr  = (int*)(adst + (size_t)n * 2);    // n
  int* cursor  = rowptr + n;                      // n
  int* bsum    = cursor + n;                      // 512
  int* pcursor = bsum + 512;                      // P
  int* deg     = pcursor + P;                     // n   (deg+pcount zeroed together)
  int* pcount  = deg + n;                         // P
  int* csr_src = pcount + P;                      // Etot
  int2* pstage = (int2*)ws;                       // Etot (aliases bufH..adst)

  const int nbN = (n + TPB - 1) / TPB;
  const int nbE = (Etot + TPB - 1) / TPB;
  const int G8  = (nbE + 7) / 8;                  // chunks per XCD for swizzled scatter
  const int nbW = (n + 3) / 4;                    // 1 wave per node, 4 waves/block

  // ---- CSR build: partition-staged counting sort (once, reused by all 3 layers) ----
  zero_kernel<<<(n + P + TPB - 1) / TPB, TPB, 0, stream>>>(deg, n + P);  // deg + pcount
  phist_kernel<<<512, TPB, 0, stream>>>(dst, E, n, pcount);
  pscan_kernel<<<1, 64, 0, stream>>>(pcount, pcursor);
  stage_kernel<<<512, TPB, 0, stream>>>(src, dst, E, n, pcursor, pstage);
  deg_hist_kernel<<<nbE, TPB, 0, stream>>>(pstage, Etot, deg);
  scanA_kernel<<<nbN, TPB, 0, stream>>>(deg, n, bsum);
  scanB_kernel<<<1, 512, 0, stream>>>(bsum, nbN);
  scanC_kernel<<<nbN, TPB, 0, stream>>>(deg, bsum, n, rowptr, cursor);
  final_scatter_kernel<<<8 * G8, TPB, 0, stream>>>(pstage, Etot, G8, cursor, csr_src);

  // ---- layer 1: in=3, out=32, H=2 ----
  transform_kernel<3, 32, 2><<<nbN, TPB, 0, stream>>>(x, W1, as1, ad1, bufH, asrc, adst, n);
  node_gat12<<<nbW, TPB, 0, stream>>>(rowptr, deg, csr_src, asrc, adst, bufH, b1, bufX, n);

  // ---- layer 2: in=32, out=32, H=2 ----
  transform_kernel<32, 32, 2><<<nbN, TPB, 0, stream>>>(bufX, W2, as2, ad2, bufH, asrc, adst, n);
  node_gat12<<<nbW, TPB, 0, stream>>>(rowptr, deg, csr_src, asrc, adst, bufH, b2, bufX, n);

  // ---- layer 3: in=32, out=16, H=1 ----
  transform_kernel<32, 16, 1><<<nbN, TPB, 0, stream>>>(bufX, W3, as3, ad3, bufH, asrc, adst, n);
  node_gat3<<<nbW, TPB, 0, stream>>>(rowptr, deg, csr_src, asrc, adst, bufH, b3, Wout, bout, out, n);
}